// Round 1
// baseline (1537.043 us; speedup 1.0000x reference)
//
#include <hip/hip_runtime.h>
#include <hip/hip_bf16.h>
#include <math.h>

// Problem constants
#define BB 4096
#define LL 16
#define SS 512
#define VV 512
#define II 512
#define HH 512

#define BK 16
#define TM 4
#define TN 4
// 64x64 tile, 16x16 threads, 4x4 micro-tile per thread.

// C[M,N] = concat_K(A0[M,KA0], A1[M,K-KA0]) @ concat_rows(B0,B1) + bias
// B row k: k < KB0 -> B0[k*N+c], else B1[(k-KB0)*N+c]
__global__ void gemm64(const float* __restrict__ A0, const float* __restrict__ A1, int KA0,
                       const float* __restrict__ B0, const float* __restrict__ B1, int KB0,
                       const float* __restrict__ bias,
                       float* __restrict__ C, int M, int N, int K) {
    __shared__ float As[64][BK + 1];
    __shared__ float Bs[BK][64 + 1];
    const int tx = threadIdx.x, ty = threadIdx.y;
    const int tid = ty * 16 + tx;
    const int brow = blockIdx.y * 64;
    const int bcol = blockIdx.x * 64;
    float acc[TM][TN] = {};
    const int nkt = K / BK;
    const int KA1 = K - KA0;
    for (int kt = 0; kt < nkt; ++kt) {
        #pragma unroll
        for (int i = 0; i < 4; ++i) {
            int e = tid + 256 * i;
            int r = e >> 4, kk = e & 15;
            int gr = brow + r, gk = kt * BK + kk;
            float v = (gk < KA0) ? A0[(size_t)gr * KA0 + gk]
                                 : A1[(size_t)gr * KA1 + (gk - KA0)];
            As[r][kk] = v;
        }
        #pragma unroll
        for (int i = 0; i < 4; ++i) {
            int e = tid + 256 * i;
            int kk = e >> 6, c = e & 63;
            int gk = kt * BK + kk, gc = bcol + c;
            float v = (gk < KB0) ? B0[(size_t)gk * N + gc]
                                 : B1[(size_t)(gk - KB0) * N + gc];
            Bs[kk][c] = v;
        }
        __syncthreads();
        #pragma unroll
        for (int kk = 0; kk < BK; ++kk) {
            float a[TM], b[TN];
            #pragma unroll
            for (int i = 0; i < TM; ++i) a[i] = As[ty * TM + i][kk];
            #pragma unroll
            for (int j = 0; j < TN; ++j) b[j] = Bs[kk][tx * TN + j];
            #pragma unroll
            for (int i = 0; i < TM; ++i)
                #pragma unroll
                for (int j = 0; j < TN; ++j)
                    acc[i][j] += a[i] * b[j];
        }
        __syncthreads();
    }
    #pragma unroll
    for (int i = 0; i < TM; ++i) {
        int gr = brow + ty * TM + i;
        #pragma unroll
        for (int j = 0; j < TN; ++j) {
            int gc = bcol + tx * TN + j;
            C[(size_t)gr * N + gc] = acc[i][j] + bias[gc];
        }
    }
}

// s[m] = sum_v tanh( (AS @ Km)[m,v] + Y[m>>4, v] ) * vsum[v]
// AS: [B*L, 512] row-major, Km: [512,512], Y: [B,512]
__global__ void attn_score(const float* __restrict__ AS,
                           const float* __restrict__ Km,
                           const float* __restrict__ Y,
                           const float* __restrict__ vsum,
                           float* __restrict__ Sout) {
    __shared__ float As[64][BK + 1];
    __shared__ float Bs[BK][64 + 1];
    __shared__ float red[64][17];
    const int tx = threadIdx.x, ty = threadIdx.y;
    const int tid = ty * 16 + tx;
    const int brow = blockIdx.x * 64;
    float rowsum[TM] = {};
    for (int ct = 0; ct < VV / 64; ++ct) {
        float acc[TM][TN] = {};
        for (int kt = 0; kt < SS / BK; ++kt) {
            #pragma unroll
            for (int i = 0; i < 4; ++i) {
                int e = tid + 256 * i;
                int r = e >> 4, kk = e & 15;
                As[r][kk] = AS[(size_t)(brow + r) * SS + kt * BK + kk];
            }
            #pragma unroll
            for (int i = 0; i < 4; ++i) {
                int e = tid + 256 * i;
                int kk = e >> 6, c = e & 63;
                Bs[kk][c] = Km[(size_t)(kt * BK + kk) * VV + ct * 64 + c];
            }
            __syncthreads();
            #pragma unroll
            for (int kk = 0; kk < BK; ++kk) {
                float a[TM], b[TN];
                #pragma unroll
                for (int i = 0; i < TM; ++i) a[i] = As[ty * TM + i][kk];
                #pragma unroll
                for (int j = 0; j < TN; ++j) b[j] = Bs[kk][tx * TN + j];
                #pragma unroll
                for (int i = 0; i < TM; ++i)
                    #pragma unroll
                    for (int j = 0; j < TN; ++j)
                        acc[i][j] += a[i] * b[j];
            }
            __syncthreads();
        }
        #pragma unroll
        for (int i = 0; i < TM; ++i) {
            int m = brow + ty * TM + i;
            int b = m >> 4;  // row m = b*L + l, L=16
            #pragma unroll
            for (int j = 0; j < TN; ++j) {
                int vcol = ct * 64 + tx * TN + j;
                float t = tanhf(acc[i][j] + Y[(size_t)b * VV + vcol]);
                rowsum[i] += t * vsum[vcol];
            }
        }
    }
    #pragma unroll
    for (int i = 0; i < TM; ++i) red[ty * TM + i][tx] = rowsum[i];
    __syncthreads();
    if (tid < 64) {
        float s = 0.f;
        #pragma unroll
        for (int t = 0; t < 16; ++t) s += red[tid][t];
        Sout[brow + tid] = s;
    }
}

// LSTM elementwise: gates [B,4H] order i,f,g,o
__global__ void lstm_ew(const float* __restrict__ gates, const float* __restrict__ cc,
                        float* __restrict__ c_new, float* __restrict__ h_new, int n) {
    int idx = blockIdx.x * blockDim.x + threadIdx.x;
    if (idx >= n) return;
    int b = idx >> 9, h = idx & 511;
    const float* g = gates + (size_t)b * (4 * HH);
    float gi = g[h], gf = g[h + HH], gg = g[h + 2 * HH], go = g[h + 3 * HH];
    float si = 1.f / (1.f + expf(-gi));
    float sf = 1.f / (1.f + expf(-gf));
    float so = 1.f / (1.f + expf(-go));
    float c = sf * cc[idx] + si * tanhf(gg);
    float hn = so * tanhf(c);
    c_new[idx] = c;
    h_new[idx] = hn;
}

// vsum[v] = sum_s V[s,v]
__global__ void vsum_k(const float* __restrict__ Vm, float* __restrict__ out) {
    int v = threadIdx.x;  // 512 threads, 1 block
    float acc = 0.f;
    for (int s = 0; s < SS; ++s) acc += Vm[(size_t)s * VV + v];
    out[v] = acc;
}

// softmax over L=16 then d[b,:] = sum_l a_l * AS[b,l,:]
__global__ void softmax_d(const float* __restrict__ S, const float* __restrict__ AS,
                          float* __restrict__ D) {
    int b = blockIdx.x;
    __shared__ float sm[LL];
    int tid = threadIdx.x;  // 256
    if (tid < LL) sm[tid] = S[(size_t)b * LL + tid];
    __syncthreads();
    float m = -1e30f;
    #pragma unroll
    for (int l = 0; l < LL; ++l) m = fmaxf(m, sm[l]);
    float w[LL];
    float sum = 0.f;
    #pragma unroll
    for (int l = 0; l < LL; ++l) { w[l] = expf(sm[l] - m); sum += w[l]; }
    float inv = 1.f / sum;
    for (int c = tid; c < SS; c += 256) {
        float acc = 0.f;
        #pragma unroll
        for (int l = 0; l < LL; ++l)
            acc += w[l] * AS[((size_t)b * LL + l) * SS + c];
        D[(size_t)b * SS + c] = acc * inv;
    }
}

// new_attn_states: rows 0..14 shifted from AS, row 15 = output
__global__ void shift_k(const float* __restrict__ AS, const float* __restrict__ outp,
                        float* __restrict__ NS, int total) {
    int idx = blockIdx.x * blockDim.x + threadIdx.x;
    if (idx >= total) return;
    int s = idx & (SS - 1);
    int l = (idx >> 9) & (LL - 1);
    int b = idx >> 13;
    NS[idx] = (l < LL - 1) ? AS[((size_t)b * LL + l + 1) * SS + s]
                           : outp[(size_t)b * SS + s];
}

extern "C" void kernel_launch(void* const* d_in, const int* in_sizes, int n_in,
                              void* d_out, int out_size, void* d_ws, size_t ws_size,
                              hipStream_t stream) {
    const float* inputs      = (const float*)d_in[0];
    const float* cell_c      = (const float*)d_in[1];
    const float* cell_h      = (const float*)d_in[2];
    const float* attns       = (const float*)d_in[3];
    const float* attn_states = (const float*)d_in[4];
    const float* W1          = (const float*)d_in[5];
    const float* b1          = (const float*)d_in[6];
    const float* Wx          = (const float*)d_in[7];
    const float* Wh          = (const float*)d_in[8];
    const float* b_lstm      = (const float*)d_in[9];
    const float* W3          = (const float*)d_in[10];
    const float* b3          = (const float*)d_in[11];
    const float* kmat        = (const float*)d_in[12];  // [1,1,S,V]
    const float* vmat        = (const float*)d_in[13];  // [1,1,S,V]
    const float* W2          = (const float*)d_in[14];
    const float* b2          = (const float*)d_in[15];

    float* o_out = (float*)d_out;                      // [B,S]
    float* o_c   = o_out + (size_t)BB * HH;            // [B,H]
    float* o_h   = o_c   + (size_t)BB * HH;            // [B,H]
    float* o_d   = o_h   + (size_t)BB * HH;            // [B,S]
    float* o_ns  = o_d   + (size_t)BB * SS;            // [B,L*S]

    float* ws   = (float*)d_ws;
    float* ws_x     = ws;                                   // B*I
    float* ws_gates = ws_x + (size_t)BB * II;               // B*4H
    float* ws_y     = ws_gates + (size_t)BB * 4 * HH;       // B*V
    float* ws_s     = ws_y + (size_t)BB * VV;               // B*L
    float* ws_vsum  = ws_s + (size_t)BB * LL;               // V

    dim3 blk(16, 16);

    // 0. vsum
    vsum_k<<<1, 512, 0, stream>>>(vmat, ws_vsum);

    // 1. x = [inputs|attns] @ W1 + b1   (M=B, N=I, K=I+S)
    gemm64<<<dim3(II / 64, BB / 64), blk, 0, stream>>>(
        inputs, attns, II, W1, W1 + (size_t)II * II, II + SS, b1,
        ws_x, BB, II, II + SS);

    // 2. gates = [x|cell_h] @ [Wx;Wh] + b_lstm   (M=B, N=4H, K=I+H)
    gemm64<<<dim3(4 * HH / 64, BB / 64), blk, 0, stream>>>(
        ws_x, cell_h, II, Wx, Wh, II, b_lstm,
        ws_gates, BB, 4 * HH, II + HH);

    // 3. LSTM elementwise -> c_new, h_new
    {
        int n = BB * HH;
        lstm_ew<<<(n + 255) / 256, 256, 0, stream>>>(ws_gates, cell_c, o_c, o_h, n);
    }

    // 4. y = [c_new|h_new] @ W3 + b3   (M=B, N=V, K=2H)
    gemm64<<<dim3(VV / 64, BB / 64), blk, 0, stream>>>(
        o_c, o_h, HH, W3, W3 + (size_t)HH * VV, 2 * HH, b3,
        ws_y, BB, VV, 2 * HH);

    // 5. s[b,l] = sum_v tanh(hf + y) * vsum
    attn_score<<<dim3(BB * LL / 64), blk, 0, stream>>>(
        attn_states, kmat, ws_y, ws_vsum, ws_s);

    // 6. softmax + d
    softmax_d<<<BB, 256, 0, stream>>>(ws_s, attn_states, o_d);

    // 7. output = [h_new|d] @ W2 + b2   (M=B, N=S, K=H+S)
    gemm64<<<dim3(SS / 64, BB / 64), blk, 0, stream>>>(
        o_h, o_d, HH, W2, W2 + (size_t)HH * SS, HH + SS, b2,
        o_out, BB, SS, HH + SS);

    // 8. new_attn_states
    {
        int total = BB * LL * SS;
        shift_k<<<(total + 255) / 256, 256, 0, stream>>>(attn_states, o_out, o_ns, total);
    }
}

// Round 2
// 393.212 us; speedup vs baseline: 3.9089x; 3.9089x over previous
//
#include <hip/hip_runtime.h>
#include <hip/hip_bf16.h>
#include <math.h>

#define BB 4096
#define LL 16
#define SS 512
#define VV 512
#define II 512
#define HH 512

typedef __attribute__((ext_vector_type(4))) float f32x4;
typedef __attribute__((ext_vector_type(8))) short short8;

#define GLOBAL_AS __attribute__((address_space(1)))
#define LDS_AS __attribute__((address_space(3)))

__device__ __forceinline__ unsigned short f2bf(float f) {
    union { float f; unsigned u; } c; c.f = f;
    unsigned u = c.u + 0x7FFFu + ((c.u >> 16) & 1u);
    return (unsigned short)(u >> 16);
}

// ---------------------------------------------------------------------------
// MFMA GEMM: C[M,N] = A[M,K](bf16) @ Bt[N,K](bf16)^T + bias
// BM=128, BN=64, BK=64. 256 threads = 4 waves in 2x2. Wave tile 64x32.
// LDS layout: row-major [rows][64] bf16 (128B rows), 16B slots XOR-swizzled:
// physical slot = logical_slot ^ (row & 7). Staged with global_load_lds by
// pre-swizzling the GLOBAL source address (linear LDS dest).
// MODE 0: float out. MODE 1: bf16 (ushort) out.
// ---------------------------------------------------------------------------
template<int MODE>
__global__ __launch_bounds__(256) void gemm_mfma(
    const ushort* __restrict__ A, const ushort* __restrict__ Bt,
    const float* __restrict__ bias, void* __restrict__ C, int ldc,
    int M, int N, int K) {
    __shared__ ushort Als[128 * 64];
    __shared__ ushort Bls[64 * 64];
    const int tid  = threadIdx.x;
    const int lane = tid & 63;
    const int w    = tid >> 6;
    const int wm   = w >> 1, wn = w & 1;
    const int brow = blockIdx.y * 128;
    const int bcol = blockIdx.x * 64;
    const int l8   = lane >> 3;                 // 0..7 (row within chunk)
    const int gsl  = (lane & 7) ^ l8;           // swizzled 16B slot in source
    f32x4 acc[4][2] = {};
    const int nkt = K >> 6;
    for (int kt = 0; kt < nkt; ++kt) {
        __syncthreads();
        #pragma unroll
        for (int i = 0; i < 4; ++i) {           // A: 16 chunks of 1024B
            int c = w + 4 * i;
            int row = c * 8 + l8;
            const ushort* gp = A + (size_t)(brow + row) * K + (kt * 64 + gsl * 8);
            __builtin_amdgcn_global_load_lds((const GLOBAL_AS void*)gp,
                                             (LDS_AS void*)(Als + c * 512), 16, 0, 0);
        }
        #pragma unroll
        for (int i = 0; i < 2; ++i) {           // B: 8 chunks
            int c = w + 4 * i;
            int row = c * 8 + l8;
            const ushort* gp = Bt + (size_t)(bcol + row) * K + (kt * 64 + gsl * 8);
            __builtin_amdgcn_global_load_lds((const GLOBAL_AS void*)gp,
                                             (LDS_AS void*)(Bls + c * 512), 16, 0, 0);
        }
        __syncthreads();
        const char* AlsB = (const char*)Als;
        const char* BlsB = (const char*)Bls;
        #pragma unroll
        for (int kh = 0; kh < 2; ++kh) {
            int k3 = kh * 4 + (lane >> 4);      // 16B-slot index along K
            short8 a[4], b[2];
            #pragma unroll
            for (int m = 0; m < 4; ++m) {
                int row = wm * 64 + m * 16 + (lane & 15);
                a[m] = *(const short8*)(AlsB + row * 128 + (k3 ^ (row & 7)) * 16);
            }
            #pragma unroll
            for (int n = 0; n < 2; ++n) {
                int row = wn * 32 + n * 16 + (lane & 15);
                b[n] = *(const short8*)(BlsB + row * 128 + (k3 ^ (row & 7)) * 16);
            }
            #pragma unroll
            for (int m = 0; m < 4; ++m)
                #pragma unroll
                for (int n = 0; n < 2; ++n)
                    acc[m][n] = __builtin_amdgcn_mfma_f32_16x16x32_bf16(a[m], b[n], acc[m][n], 0, 0, 0);
        }
    }
    #pragma unroll
    for (int m = 0; m < 4; ++m)
        #pragma unroll
        for (int n = 0; n < 2; ++n)
            #pragma unroll
            for (int r = 0; r < 4; ++r) {
                int gm = brow + wm * 64 + m * 16 + (lane >> 4) * 4 + r;
                int gc = bcol + wn * 32 + n * 16 + (lane & 15);
                float v = acc[m][n][r] + bias[gc];
                if (MODE == 0) ((float*)C)[(size_t)gm * ldc + gc] = v;
                else           ((ushort*)C)[(size_t)gm * ldc + gc] = f2bf(v);
            }
}

// ---------------------------------------------------------------------------
// Score GEMM: spart[bx][m] = sum_{v in col-block bx} tanh((AS@K)[m,v] + Y[m>>4,v]) * vsum[v]
// A (attn_states) is fp32 in global; reg-staged with fp32->bf16 cvt into
// swizzled LDS. B (k^T bf16) via global_load_lds. Same tile geometry.
// ---------------------------------------------------------------------------
__global__ __launch_bounds__(256) void gemm_score(
    const float* __restrict__ ASf, const ushort* __restrict__ Bt,
    const float* __restrict__ Y, const float* __restrict__ vsum,
    float* __restrict__ spart) {
    __shared__ ushort Als[128 * 64];
    __shared__ ushort Bls[64 * 64];
    __shared__ float sred[2][128];
    const int tid  = threadIdx.x;
    const int lane = tid & 63;
    const int w    = tid >> 6;
    const int wm   = w >> 1, wn = w & 1;
    const int brow = blockIdx.y * 128;
    const int bcol = blockIdx.x * 64;
    const int l8   = lane >> 3;
    const int gsl  = (lane & 7) ^ l8;
    f32x4 acc[4][2] = {};
    for (int kt = 0; kt < SS / 64; ++kt) {
        __syncthreads();
        // A: 1024 16B-chunks, 4 per thread, cvt fp32->bf16, swizzled ds_write
        #pragma unroll
        for (int i = 0; i < 4; ++i) {
            int chunk = i * 256 + tid;
            int row = chunk >> 3, slot = chunk & 7;
            int gslot = slot ^ (row & 7);
            const float* gp = ASf + (size_t)(brow + row) * SS + kt * 64 + gslot * 8;
            float4 f0 = *(const float4*)gp;
            float4 f1 = *(const float4*)(gp + 4);
            short8 pk;
            pk[0] = (short)f2bf(f0.x); pk[1] = (short)f2bf(f0.y);
            pk[2] = (short)f2bf(f0.z); pk[3] = (short)f2bf(f0.w);
            pk[4] = (short)f2bf(f1.x); pk[5] = (short)f2bf(f1.y);
            pk[6] = (short)f2bf(f1.z); pk[7] = (short)f2bf(f1.w);
            *(short8*)((char*)Als + chunk * 16) = pk;
        }
        #pragma unroll
        for (int i = 0; i < 2; ++i) {
            int c = w + 4 * i;
            int row = c * 8 + l8;
            const ushort* gp = Bt + (size_t)(bcol + row) * SS + (kt * 64 + gsl * 8);
            __builtin_amdgcn_global_load_lds((const GLOBAL_AS void*)gp,
                                             (LDS_AS void*)(Bls + c * 512), 16, 0, 0);
        }
        __syncthreads();
        const char* AlsB = (const char*)Als;
        const char* BlsB = (const char*)Bls;
        #pragma unroll
        for (int kh = 0; kh < 2; ++kh) {
            int k3 = kh * 4 + (lane >> 4);
            short8 a[4], b[2];
            #pragma unroll
            for (int m = 0; m < 4; ++m) {
                int row = wm * 64 + m * 16 + (lane & 15);
                a[m] = *(const short8*)(AlsB + row * 128 + (k3 ^ (row & 7)) * 16);
            }
            #pragma unroll
            for (int n = 0; n < 2; ++n) {
                int row = wn * 32 + n * 16 + (lane & 15);
                b[n] = *(const short8*)(BlsB + row * 128 + (k3 ^ (row & 7)) * 16);
            }
            #pragma unroll
            for (int m = 0; m < 4; ++m)
                #pragma unroll
                for (int n = 0; n < 2; ++n)
                    acc[m][n] = __builtin_amdgcn_mfma_f32_16x16x32_bf16(a[m], b[n], acc[m][n], 0, 0, 0);
        }
    }
    // fused epilogue: tanh + vsum-weighted row reduction
    float part[4][4] = {};
    #pragma unroll
    for (int m = 0; m < 4; ++m)
        #pragma unroll
        for (int n = 0; n < 2; ++n)
            #pragma unroll
            for (int r = 0; r < 4; ++r) {
                int gm = brow + wm * 64 + m * 16 + (lane >> 4) * 4 + r;
                int gc = bcol + wn * 32 + n * 16 + (lane & 15);
                float t = tanhf(acc[m][n][r] + Y[(size_t)(gm >> 4) * VV + gc]);
                part[m][r] += t * vsum[gc];
            }
    #pragma unroll
    for (int m = 0; m < 4; ++m)
        #pragma unroll
        for (int r = 0; r < 4; ++r) {
            float v = part[m][r];
            v += __shfl_xor(v, 1); v += __shfl_xor(v, 2);
            v += __shfl_xor(v, 4); v += __shfl_xor(v, 8);
            if ((lane & 15) == 0)
                sred[wn][wm * 64 + m * 16 + (lane >> 4) * 4 + r] = v;
        }
    __syncthreads();
    if (tid < 128)
        spart[(size_t)blockIdx.x * (BB * LL) + brow + tid] = sred[0][tid] + sred[1][tid];
}

__global__ void reduce_s(const float* __restrict__ spart, float* __restrict__ s) {
    int i = blockIdx.x * 256 + threadIdx.x;
    float v = 0.f;
    #pragma unroll
    for (int j = 0; j < 8; ++j) v += spart[(size_t)j * (BB * LL) + i];
    s[i] = v;
}

// transpose + cvt: dst[n][k] = (k<K0 ? srcA[k][n] : srcB[k-K0][n]) as bf16
__global__ void tr_cvt(const float* __restrict__ srcA, const float* __restrict__ srcB,
                       int K0, ushort* __restrict__ dst, int N, int K) {
    __shared__ float tile[32][33];
    int bn = blockIdx.x, bk = blockIdx.y;
    int tx = threadIdx.x, ty = threadIdx.y;  // 32 x 8
    #pragma unroll
    for (int j = 0; j < 4; ++j) {
        int k = bk * 32 + ty + j * 8;
        const float* s = (k < K0) ? (srcA + (size_t)k * N) : (srcB + (size_t)(k - K0) * N);
        tile[ty + j * 8][tx] = s[bn * 32 + tx];
    }
    __syncthreads();
    #pragma unroll
    for (int j = 0; j < 4; ++j) {
        int n = bn * 32 + ty + j * 8;
        dst[(size_t)n * K + bk * 32 + tx] = f2bf(tile[tx][ty + j * 8]);
    }
}

// fp32 [M][512] -> bf16 rows at dst stride (for packing concat A operands)
__global__ void cvt_strided(const float* __restrict__ src, ushort* __restrict__ dst,
                            int dstride) {
    int idx = blockIdx.x * 256 + threadIdx.x;
    int i4 = idx & 127, row = idx >> 7;
    float4 v = *(const float4*)(src + (size_t)row * 512 + i4 * 4);
    ushort4 o; o.x = f2bf(v.x); o.y = f2bf(v.y); o.z = f2bf(v.z); o.w = f2bf(v.w);
    *(ushort4*)(dst + (size_t)row * dstride + i4 * 4) = o;
}

__global__ void lstm_ew(const float* __restrict__ gates, const float* __restrict__ cc,
                        float* __restrict__ c_new, float* __restrict__ h_new,
                        ushort* __restrict__ A4, ushort* __restrict__ A7) {
    int idx = blockIdx.x * 256 + threadIdx.x;
    int b = idx >> 9, h = idx & 511;
    const float* g = gates + (size_t)b * (4 * HH);
    float gi = g[h], gf = g[h + HH], gg = g[h + 2 * HH], go = g[h + 3 * HH];
    float si = 1.f / (1.f + expf(-gi));
    float sf = 1.f / (1.f + expf(-gf));
    float so = 1.f / (1.f + expf(-go));
    float c = sf * cc[idx] + si * tanhf(gg);
    float hn = so * tanhf(c);
    c_new[idx] = c;
    h_new[idx] = hn;
    A4[(size_t)b * 1024 + h] = f2bf(c);
    A4[(size_t)b * 1024 + 512 + h] = f2bf(hn);
    A7[(size_t)b * 1024 + h] = f2bf(hn);
}

__global__ void vsum_k(const float* __restrict__ Vm, float* __restrict__ out) {
    int v = threadIdx.x;
    float acc = 0.f;
    for (int s = 0; s < SS; ++s) acc += Vm[(size_t)s * VV + v];
    out[v] = acc;
}

// softmax over L + d = a @ attn_states; writes fp32 d and bf16 into A7 right half
__global__ void softmax_d(const float* __restrict__ S, const float* __restrict__ AS,
                          float* __restrict__ D, ushort* __restrict__ A7) {
    int b = blockIdx.x;
    int tid = threadIdx.x;  // 128
    __shared__ float sm[LL];
    if (tid < LL) sm[tid] = S[(size_t)b * LL + tid];
    __syncthreads();
    float m = -1e30f;
    #pragma unroll
    for (int l = 0; l < LL; ++l) m = fmaxf(m, sm[l]);
    float wgt[LL]; float sum = 0.f;
    #pragma unroll
    for (int l = 0; l < LL; ++l) { wgt[l] = expf(sm[l] - m); sum += wgt[l]; }
    float inv = 1.f / sum;
    const float4* AS4 = (const float4*)AS;
    float4 acc = {0.f, 0.f, 0.f, 0.f};
    #pragma unroll
    for (int l = 0; l < LL; ++l) {
        float4 v = AS4[((size_t)b * LL + l) * 128 + tid];
        acc.x += wgt[l] * v.x; acc.y += wgt[l] * v.y;
        acc.z += wgt[l] * v.z; acc.w += wgt[l] * v.w;
    }
    acc.x *= inv; acc.y *= inv; acc.z *= inv; acc.w *= inv;
    ((float4*)D)[(size_t)b * 128 + tid] = acc;
    ushort4 o; o.x = f2bf(acc.x); o.y = f2bf(acc.y); o.z = f2bf(acc.z); o.w = f2bf(acc.w);
    *(ushort4*)(A7 + (size_t)b * 1024 + 512 + tid * 4) = o;
}

__global__ void shift_k(const float4* __restrict__ AS4, const float4* __restrict__ out4,
                        float4* __restrict__ NS4) {
    int idx = blockIdx.x * 256 + threadIdx.x;   // BB*LL*128 total
    int s4 = idx & 127, l = (idx >> 7) & 15, b = idx >> 11;
    NS4[idx] = (l < LL - 1) ? AS4[((size_t)b * LL + l + 1) * 128 + s4]
                            : out4[(size_t)b * 128 + s4];
}

extern "C" void kernel_launch(void* const* d_in, const int* in_sizes, int n_in,
                              void* d_out, int out_size, void* d_ws, size_t ws_size,
                              hipStream_t stream) {
    const float* inputs      = (const float*)d_in[0];
    const float* cell_c      = (const float*)d_in[1];
    const float* cell_h      = (const float*)d_in[2];
    const float* attns       = (const float*)d_in[3];
    const float* attn_states = (const float*)d_in[4];
    const float* W1          = (const float*)d_in[5];
    const float* b1          = (const float*)d_in[6];
    const float* Wx          = (const float*)d_in[7];
    const float* Wh          = (const float*)d_in[8];
    const float* b_lstm      = (const float*)d_in[9];
    const float* W3          = (const float*)d_in[10];
    const float* b3          = (const float*)d_in[11];
    const float* kmat        = (const float*)d_in[12];
    const float* vmat        = (const float*)d_in[13];
    const float* W2          = (const float*)d_in[14];
    const float* b2          = (const float*)d_in[15];

    float* o_out = (float*)d_out;
    float* o_c   = o_out + (size_t)BB * HH;
    float* o_h   = o_c   + (size_t)BB * HH;
    float* o_d   = o_h   + (size_t)BB * HH;
    float* o_ns  = o_d   + (size_t)BB * SS;

    float* ws_gates = (float*)d_ws;                          // B*4H
    float* ws_y     = ws_gates + (size_t)BB * 4 * HH;        // B*V
    float* ws_s     = ws_y + (size_t)BB * VV;                // B*L
    float* ws_spart = ws_s + (size_t)BB * LL;                // 8*B*L
    float* ws_vsum  = ws_spart + (size_t)8 * BB * LL;        // V
    ushort* A1    = (ushort*)(ws_vsum + VV);                 // [B][1024]
    ushort* A2    = A1 + (size_t)BB * 1024;
    ushort* A4    = A2 + (size_t)BB * 1024;
    ushort* A7    = A4 + (size_t)BB * 1024;
    ushort* W1t   = A7 + (size_t)BB * 1024;                  // [512][1024]
    ushort* WxWht = W1t + (size_t)512 * 1024;                // [2048][1024]
    ushort* W3t   = WxWht + (size_t)2048 * 1024;             // [512][1024]
    ushort* W2t   = W3t + (size_t)512 * 1024;                // [512][1024]
    ushort* kTt   = W2t + (size_t)512 * 1024;                // [512][512]

    dim3 trb(32, 8);
    // weight prep (independent)
    tr_cvt<<<dim3(512 / 32, 1024 / 32), trb, 0, stream>>>(W1, W1, 1024, W1t, 512, 1024);
    tr_cvt<<<dim3(2048 / 32, 1024 / 32), trb, 0, stream>>>(Wx, Wh, 512, WxWht, 2048, 1024);
    tr_cvt<<<dim3(512 / 32, 1024 / 32), trb, 0, stream>>>(W3, W3, 1024, W3t, 512, 1024);
    tr_cvt<<<dim3(512 / 32, 1024 / 32), trb, 0, stream>>>(W2, W2, 1024, W2t, 512, 1024);
    tr_cvt<<<dim3(512 / 32, 512 / 32), trb, 0, stream>>>(kmat, kmat, 512, kTt, 512, 512);
    vsum_k<<<1, 512, 0, stream>>>(vmat, ws_vsum);
    // activation packing
    cvt_strided<<<BB * 128 / 256, 256, 0, stream>>>(inputs, A1, 1024);
    cvt_strided<<<BB * 128 / 256, 256, 0, stream>>>(attns, A1 + 512, 1024);
    cvt_strided<<<BB * 128 / 256, 256, 0, stream>>>(cell_h, A2 + 512, 1024);

    // 1. x = [inputs|attns] @ W1 + b1 -> bf16 into A2 left half
    gemm_mfma<1><<<dim3(512 / 64, BB / 128), 256, 0, stream>>>(
        A1, W1t, b1, A2, 1024, BB, 512, 1024);
    // 2. gates = [x|cell_h] @ [Wx;Wh] + b_lstm
    gemm_mfma<0><<<dim3(2048 / 64, BB / 128), 256, 0, stream>>>(
        A2, WxWht, b_lstm, ws_gates, 2048, BB, 2048, 1024);
    // 3. LSTM elementwise
    lstm_ew<<<BB * HH / 256, 256, 0, stream>>>(ws_gates, cell_c, o_c, o_h, A4, A7);
    // 4. y = [c|h] @ W3 + b3
    gemm_mfma<0><<<dim3(512 / 64, BB / 128), 256, 0, stream>>>(
        A4, W3t, b3, ws_y, 512, BB, 512, 1024);
    // 5. score partials
    gemm_score<<<dim3(512 / 64, BB * LL / 128), 256, 0, stream>>>(
        attn_states, kTt, ws_y, ws_vsum, ws_spart);
    reduce_s<<<BB * LL / 256, 256, 0, stream>>>(ws_spart, ws_s);
    // 6. softmax + d (fp32 d + bf16 into A7 right half)
    softmax_d<<<BB, 128, 0, stream>>>(ws_s, attn_states, o_d, A7);
    // 7. output = [h|d] @ W2 + b2
    gemm_mfma<0><<<dim3(512 / 64, BB / 128), 256, 0, stream>>>(
        A7, W2t, b2, o_out, 512, BB, 512, 1024);
    // 8. shift window
    shift_k<<<BB * LL * 128 / 256, 256, 0, stream>>>(
        (const float4*)attn_states, (const float4*)o_out, (float4*)o_ns);
}

// Round 3
// 329.985 us; speedup vs baseline: 4.6579x; 1.1916x over previous
//
#include <hip/hip_runtime.h>
#include <hip/hip_bf16.h>
#include <math.h>

#define BB 4096
#define LL 16
#define SS 512
#define VV 512
#define II 512
#define HH 512

typedef __attribute__((ext_vector_type(4))) float f32x4;
typedef __attribute__((ext_vector_type(8))) short short8;

#define GLOBAL_AS __attribute__((address_space(1)))
#define LDS_AS __attribute__((address_space(3)))

__device__ __forceinline__ unsigned short f2bf(float f) {
    union { float f; unsigned u; } c; c.f = f;
    unsigned u = c.u + 0x7FFFu + ((c.u >> 16) & 1u);
    return (unsigned short)(u >> 16);
}
__device__ __forceinline__ float bf2f(unsigned short u) {
    union { unsigned u; float f; } c; c.u = ((unsigned)u) << 16;
    return c.f;
}
__device__ __forceinline__ float fast_tanh(float x) {
    // tanh(x) = 1 - 2/(exp(2x)+1); saturates correctly at +-inf
    return 1.f - 2.f / (__expf(2.f * x) + 1.f);
}

// ---------------------------------------------------------------------------
// MFMA GEMM: C[M,N] = A[M,K](bf16) @ Bt[N,K](bf16)^T + bias
// BM=128, BN=64, BK=64. 256 threads = 4 waves in 2x2. Wave tile 64x32.
// MODE 0: float out. MODE 1: bf16 out. MODE 2: float out + copy into
//         C2[(row*16+15)*512 + col] (o_ns last row).
// ---------------------------------------------------------------------------
template<int MODE>
__global__ __launch_bounds__(256) void gemm_mfma(
    const ushort* __restrict__ A, const ushort* __restrict__ Bt,
    const float* __restrict__ bias, void* __restrict__ C, float* __restrict__ C2,
    int ldc, int M, int N, int K) {
    __shared__ ushort Als[128 * 64];
    __shared__ ushort Bls[64 * 64];
    const int tid  = threadIdx.x;
    const int lane = tid & 63;
    const int w    = tid >> 6;
    const int wm   = w >> 1, wn = w & 1;
    const int brow = blockIdx.y * 128;
    const int bcol = blockIdx.x * 64;
    const int l8   = lane >> 3;
    const int gsl  = (lane & 7) ^ l8;
    f32x4 acc[4][2] = {};
    const int nkt = K >> 6;
    for (int kt = 0; kt < nkt; ++kt) {
        __syncthreads();
        #pragma unroll
        for (int i = 0; i < 4; ++i) {
            int c = w + 4 * i;
            int row = c * 8 + l8;
            const ushort* gp = A + (size_t)(brow + row) * K + (kt * 64 + gsl * 8);
            __builtin_amdgcn_global_load_lds((const GLOBAL_AS void*)gp,
                                             (LDS_AS void*)(Als + c * 512), 16, 0, 0);
        }
        #pragma unroll
        for (int i = 0; i < 2; ++i) {
            int c = w + 4 * i;
            int row = c * 8 + l8;
            const ushort* gp = Bt + (size_t)(bcol + row) * K + (kt * 64 + gsl * 8);
            __builtin_amdgcn_global_load_lds((const GLOBAL_AS void*)gp,
                                             (LDS_AS void*)(Bls + c * 512), 16, 0, 0);
        }
        __syncthreads();
        const char* AlsB = (const char*)Als;
        const char* BlsB = (const char*)Bls;
        #pragma unroll
        for (int kh = 0; kh < 2; ++kh) {
            int k3 = kh * 4 + (lane >> 4);
            short8 a[4], b[2];
            #pragma unroll
            for (int m = 0; m < 4; ++m) {
                int row = wm * 64 + m * 16 + (lane & 15);
                a[m] = *(const short8*)(AlsB + row * 128 + (k3 ^ (row & 7)) * 16);
            }
            #pragma unroll
            for (int n = 0; n < 2; ++n) {
                int row = wn * 32 + n * 16 + (lane & 15);
                b[n] = *(const short8*)(BlsB + row * 128 + (k3 ^ (row & 7)) * 16);
            }
            #pragma unroll
            for (int m = 0; m < 4; ++m)
                #pragma unroll
                for (int n = 0; n < 2; ++n)
                    acc[m][n] = __builtin_amdgcn_mfma_f32_16x16x32_bf16(a[m], b[n], acc[m][n], 0, 0, 0);
        }
    }
    #pragma unroll
    for (int m = 0; m < 4; ++m)
        #pragma unroll
        for (int n = 0; n < 2; ++n)
            #pragma unroll
            for (int r = 0; r < 4; ++r) {
                int gm = brow + wm * 64 + m * 16 + (lane >> 4) * 4 + r;
                int gc = bcol + wn * 32 + n * 16 + (lane & 15);
                float v = acc[m][n][r] + bias[gc];
                if (MODE == 1) ((ushort*)C)[(size_t)gm * ldc + gc] = f2bf(v);
                else           ((float*)C)[(size_t)gm * ldc + gc] = v;
                if (MODE == 2) C2[((size_t)gm * 16 + 15) * 512 + gc] = v;
            }
}

// ---------------------------------------------------------------------------
// Fused: score GEMM (AS@k^T w/ tanh*vsum epilogue) + softmax + d + shifted
// o_ns rows 0..14. One block = 128 AS rows = 8 complete batches.
// A resident in 128KB LDS (bf16, swizzled); k^T streamed in 8KB dbuf tiles.
// ---------------------------------------------------------------------------
__global__ __launch_bounds__(256) void score_fused(
    const float* __restrict__ ASf, const ushort* __restrict__ Bt,
    const float* __restrict__ Y, const float* __restrict__ vsum,
    float* __restrict__ o_ns, float* __restrict__ o_d, ushort* __restrict__ A7) {
    __shared__ ushort Als[128 * 512];     // 128 KB
    __shared__ ushort Bls[2][64 * 64];    // 16 KB
    __shared__ float sred[2][128];
    __shared__ float s_lds[128];
    const int tid  = threadIdx.x;
    const int lane = tid & 63;
    const int w    = tid >> 6;
    const int wm   = w >> 1, wn = w & 1;
    const int brow = blockIdx.x * 128;
    char* AlsB = (char*)Als;

    // ---- Stage A: fp32 -> bf16 swizzled LDS; pass-through shifted o_ns ----
    #pragma unroll 8
    for (int i = 0; i < 32; ++i) {
        int c = i * 256 + tid;            // 16B-chunk id, 0..8191
        int row = c >> 6, slot = c & 63;
        const float* gp = ASf + (size_t)(brow + row) * 512 + slot * 8;
        float4 f0 = *(const float4*)gp;
        float4 f1 = *(const float4*)(gp + 4);
        int gr = brow + row;
        if ((gr & 15) > 0) {              // row l -> o_ns row l-1 (same batch)
            float* op = o_ns + (size_t)(gr - 1) * 512 + slot * 8;
            *(float4*)op = f0;
            *(float4*)(op + 4) = f1;
        }
        short8 pk;
        pk[0] = (short)f2bf(f0.x); pk[1] = (short)f2bf(f0.y);
        pk[2] = (short)f2bf(f0.z); pk[3] = (short)f2bf(f0.w);
        pk[4] = (short)f2bf(f1.x); pk[5] = (short)f2bf(f1.y);
        pk[6] = (short)f2bf(f1.z); pk[7] = (short)f2bf(f1.w);
        *(short8*)(AlsB + (row * 64 + (slot ^ (row & 7))) * 16) = pk;
    }

    // ---- main loop: 8 col-blocks x 8 K-tiles, dbuf B ----
    auto stageB = [&](int it, int buf) {
        int cb = it >> 3, kt = it & 7;
        #pragma unroll
        for (int i = 0; i < 2; ++i) {
            int c = w * 128 + i * 64 + lane;
            int row = c >> 3, slot = c & 7;
            const ushort* gp = Bt + (size_t)(cb * 64 + row) * 512 + kt * 64
                               + ((slot ^ (row & 7)) * 8);
            __builtin_amdgcn_global_load_lds((const GLOBAL_AS void*)gp,
                (LDS_AS void*)(Bls[buf] + c * 8), 16, 0, 0);
        }
    };

    float rowsum[4][4] = {};
    stageB(0, 0);
    int cur = 0;
    for (int cb = 0; cb < 8; ++cb) {
        f32x4 acc[4][2] = {};
        for (int kt = 0; kt < 8; ++kt) {
            __syncthreads();              // drains prev prefetch; guards buffers
            int nit = cb * 8 + kt + 1;
            if (nit < 64) stageB(nit, cur ^ 1);
            const char* BlsB = (const char*)Bls[cur];
            #pragma unroll
            for (int kh = 0; kh < 2; ++kh) {
                int ks = kt * 2 + kh;
                short8 a[4], b[2];
                #pragma unroll
                for (int m = 0; m < 4; ++m) {
                    int row = wm * 64 + m * 16 + (lane & 15);
                    int slot = (ks * 4 + (lane >> 4)) ^ (row & 7);
                    a[m] = *(const short8*)(AlsB + (row * 64 + slot) * 16);
                }
                int k3 = kh * 4 + (lane >> 4);
                #pragma unroll
                for (int n = 0; n < 2; ++n) {
                    int row = wn * 32 + n * 16 + (lane & 15);
                    b[n] = *(const short8*)(BlsB + row * 128 + (k3 ^ (row & 7)) * 16);
                }
                #pragma unroll
                for (int m = 0; m < 4; ++m)
                    #pragma unroll
                    for (int n = 0; n < 2; ++n)
                        acc[m][n] = __builtin_amdgcn_mfma_f32_16x16x32_bf16(a[m], b[n], acc[m][n], 0, 0, 0);
            }
            cur ^= 1;
        }
        // fused epilogue for this col-block (overlaps next cb's first prefetch)
        #pragma unroll
        for (int m = 0; m < 4; ++m) {
            int yb = (brow >> 4) + wm * 4 + m;
            #pragma unroll
            for (int n = 0; n < 2; ++n) {
                int gc = cb * 64 + wn * 32 + n * 16 + (lane & 15);
                float yv = Y[(size_t)yb * VV + gc];
                float vs = vsum[gc];
                #pragma unroll
                for (int r = 0; r < 4; ++r)
                    rowsum[m][r] += fast_tanh(acc[m][n][r] + yv) * vs;
            }
        }
    }
    // ---- reduce s across lanes ----
    #pragma unroll
    for (int m = 0; m < 4; ++m)
        #pragma unroll
        for (int r = 0; r < 4; ++r) {
            float v = rowsum[m][r];
            v += __shfl_xor(v, 1); v += __shfl_xor(v, 2);
            v += __shfl_xor(v, 4); v += __shfl_xor(v, 8);
            if ((lane & 15) == 0)
                sred[wn][wm * 64 + m * 16 + (lane >> 4) * 4 + r] = v;
        }
    __syncthreads();
    if (tid < 128) s_lds[tid] = sred[0][tid] + sred[1][tid];
    __syncthreads();

    // ---- softmax over L=16 + d from LDS ----
    const int b8 = tid >> 5;              // local batch 0..7
    const int sl = tid & 31;              // slot lane
    const int bg = (brow >> 4) + b8;      // global batch
    float mx = -1e30f;
    #pragma unroll
    for (int l = 0; l < LL; ++l) mx = fmaxf(mx, s_lds[b8 * 16 + l]);
    float wgt[LL]; float sum = 0.f;
    #pragma unroll
    for (int l = 0; l < LL; ++l) { wgt[l] = __expf(s_lds[b8 * 16 + l] - mx); sum += wgt[l]; }
    const float inv = 1.f / sum;
    #pragma unroll
    for (int half = 0; half < 2; ++half) {
        int slot = sl + 32 * half;
        float accv[8] = {};
        #pragma unroll
        for (int l = 0; l < LL; ++l) {
            int row = b8 * 16 + l;
            short8 a = *(const short8*)(AlsB + (row * 64 + (slot ^ (row & 7))) * 16);
            #pragma unroll
            for (int j = 0; j < 8; ++j)
                accv[j] += wgt[l] * bf2f((unsigned short)a[j]);
        }
        float4 o0, o1;
        o0.x = accv[0] * inv; o0.y = accv[1] * inv; o0.z = accv[2] * inv; o0.w = accv[3] * inv;
        o1.x = accv[4] * inv; o1.y = accv[5] * inv; o1.z = accv[6] * inv; o1.w = accv[7] * inv;
        float* dp = o_d + (size_t)bg * 512 + slot * 8;
        *(float4*)dp = o0; *(float4*)(dp + 4) = o1;
        ushort4 u0, u1;
        u0.x = f2bf(o0.x); u0.y = f2bf(o0.y); u0.z = f2bf(o0.z); u0.w = f2bf(o0.w);
        u1.x = f2bf(o1.x); u1.y = f2bf(o1.y); u1.z = f2bf(o1.z); u1.w = f2bf(o1.w);
        ushort* ap = A7 + (size_t)bg * 1024 + 512 + slot * 8;
        *(ushort4*)ap = u0; *(ushort4*)(ap + 4) = u1;
    }
}

// transpose + cvt: dst[n][k] = (k<K0 ? srcA[k][n] : srcB[k-K0][n]) as bf16
__global__ void tr_cvt(const float* __restrict__ srcA, const float* __restrict__ srcB,
                       int K0, ushort* __restrict__ dst, int N, int K) {
    __shared__ float tile[32][33];
    int bn = blockIdx.x, bk = blockIdx.y;
    int tx = threadIdx.x, ty = threadIdx.y;  // 32 x 8
    #pragma unroll
    for (int j = 0; j < 4; ++j) {
        int k = bk * 32 + ty + j * 8;
        const float* s = (k < K0) ? (srcA + (size_t)k * N) : (srcB + (size_t)(k - K0) * N);
        tile[ty + j * 8][tx] = s[bn * 32 + tx];
    }
    __syncthreads();
    #pragma unroll
    for (int j = 0; j < 4; ++j) {
        int n = bn * 32 + ty + j * 8;
        dst[(size_t)n * K + bk * 32 + tx] = f2bf(tile[tx][ty + j * 8]);
    }
}

__global__ void cvt_strided(const float* __restrict__ src, ushort* __restrict__ dst,
                            int dstride) {
    int idx = blockIdx.x * 256 + threadIdx.x;
    int i4 = idx & 127, row = idx >> 7;
    float4 v = *(const float4*)(src + (size_t)row * 512 + i4 * 4);
    ushort4 o; o.x = f2bf(v.x); o.y = f2bf(v.y); o.z = f2bf(v.z); o.w = f2bf(v.w);
    *(ushort4*)(dst + (size_t)row * dstride + i4 * 4) = o;
}

__global__ void lstm_ew(const float* __restrict__ gates, const float* __restrict__ cc,
                        float* __restrict__ c_new, float* __restrict__ h_new,
                        ushort* __restrict__ A4, ushort* __restrict__ A7) {
    int idx = blockIdx.x * 256 + threadIdx.x;
    int b = idx >> 9, h = idx & 511;
    const float* g = gates + (size_t)b * (4 * HH);
    float gi = g[h], gf = g[h + HH], gg = g[h + 2 * HH], go = g[h + 3 * HH];
    float si = 1.f / (1.f + __expf(-gi));
    float sf = 1.f / (1.f + __expf(-gf));
    float so = 1.f / (1.f + __expf(-go));
    float c = sf * cc[idx] + si * tanhf(gg);
    float hn = so * tanhf(c);
    c_new[idx] = c;
    h_new[idx] = hn;
    A4[(size_t)b * 1024 + h] = f2bf(c);
    A4[(size_t)b * 1024 + 512 + h] = f2bf(hn);
    A7[(size_t)b * 1024 + h] = f2bf(hn);
}

__global__ void vsum_k(const float* __restrict__ Vm, float* __restrict__ out) {
    int v = threadIdx.x;
    float acc = 0.f;
    for (int s = 0; s < SS; ++s) acc += Vm[(size_t)s * VV + v];
    out[v] = acc;
}

extern "C" void kernel_launch(void* const* d_in, const int* in_sizes, int n_in,
                              void* d_out, int out_size, void* d_ws, size_t ws_size,
                              hipStream_t stream) {
    const float* inputs      = (const float*)d_in[0];
    const float* cell_c      = (const float*)d_in[1];
    const float* cell_h      = (const float*)d_in[2];
    const float* attns       = (const float*)d_in[3];
    const float* attn_states = (const float*)d_in[4];
    const float* W1          = (const float*)d_in[5];
    const float* b1          = (const float*)d_in[6];
    const float* Wx          = (const float*)d_in[7];
    const float* Wh          = (const float*)d_in[8];
    const float* b_lstm      = (const float*)d_in[9];
    const float* W3          = (const float*)d_in[10];
    const float* b3          = (const float*)d_in[11];
    const float* kmat        = (const float*)d_in[12];
    const float* vmat        = (const float*)d_in[13];
    const float* W2          = (const float*)d_in[14];
    const float* b2          = (const float*)d_in[15];

    float* o_out = (float*)d_out;
    float* o_c   = o_out + (size_t)BB * HH;
    float* o_h   = o_c   + (size_t)BB * HH;
    float* o_d   = o_h   + (size_t)BB * HH;
    float* o_ns  = o_d   + (size_t)BB * SS;

    float* ws_gates = (float*)d_ws;                          // B*4H
    float* ws_y     = ws_gates + (size_t)BB * 4 * HH;        // B*V
    float* ws_vsum  = ws_y + (size_t)BB * VV;                // V
    ushort* A1    = (ushort*)(ws_vsum + VV);                 // [B][1024]
    ushort* A2    = A1 + (size_t)BB * 1024;
    ushort* A4    = A2 + (size_t)BB * 1024;
    ushort* A7    = A4 + (size_t)BB * 1024;
    ushort* W1t   = A7 + (size_t)BB * 1024;                  // [512][1024]
    ushort* WxWht = W1t + (size_t)512 * 1024;                // [2048][1024]
    ushort* W3t   = WxWht + (size_t)2048 * 1024;             // [512][1024]
    ushort* W2t   = W3t + (size_t)512 * 1024;                // [512][1024]
    ushort* kTt   = W2t + (size_t)512 * 1024;                // [512][512]

    dim3 trb(32, 8);
    tr_cvt<<<dim3(512 / 32, 1024 / 32), trb, 0, stream>>>(W1, W1, 1024, W1t, 512, 1024);
    tr_cvt<<<dim3(2048 / 32, 1024 / 32), trb, 0, stream>>>(Wx, Wh, 512, WxWht, 2048, 1024);
    tr_cvt<<<dim3(512 / 32, 1024 / 32), trb, 0, stream>>>(W3, W3, 1024, W3t, 512, 1024);
    tr_cvt<<<dim3(512 / 32, 1024 / 32), trb, 0, stream>>>(W2, W2, 1024, W2t, 512, 1024);
    tr_cvt<<<dim3(512 / 32, 512 / 32), trb, 0, stream>>>(kmat, kmat, 512, kTt, 512, 512);
    vsum_k<<<1, 512, 0, stream>>>(vmat, ws_vsum);
    cvt_strided<<<BB * 128 / 256, 256, 0, stream>>>(inputs, A1, 1024);
    cvt_strided<<<BB * 128 / 256, 256, 0, stream>>>(attns, A1 + 512, 1024);
    cvt_strided<<<BB * 128 / 256, 256, 0, stream>>>(cell_h, A2 + 512, 1024);

    // 1. x = [inputs|attns] @ W1 + b1 -> bf16 into A2 left half
    gemm_mfma<1><<<dim3(512 / 64, BB / 128), 256, 0, stream>>>(
        A1, W1t, b1, A2, nullptr, 1024, BB, 512, 1024);
    // 2. gates = [x|cell_h] @ [Wx;Wh] + b_lstm
    gemm_mfma<0><<<dim3(2048 / 64, BB / 128), 256, 0, stream>>>(
        A2, WxWht, b_lstm, ws_gates, nullptr, 2048, BB, 2048, 1024);
    // 3. LSTM elementwise
    lstm_ew<<<BB * HH / 256, 256, 0, stream>>>(ws_gates, cell_c, o_c, o_h, A4, A7);
    // 4. y = [c|h] @ W3 + b3
    gemm_mfma<0><<<dim3(512 / 64, BB / 128), 256, 0, stream>>>(
        A4, W3t, b3, ws_y, nullptr, 512, BB, 512, 1024);
    // 5-6-8a. fused score + softmax + d + shifted o_ns rows 0..14
    score_fused<<<BB * LL / 128, 256, 0, stream>>>(
        attn_states, kTt, ws_y, ws_vsum, o_ns, o_d, A7);
    // 7+8b. output = [h|d] @ W2 + b2 (also writes o_ns row 15)
    gemm_mfma<2><<<dim3(512 / 64, BB / 128), 256, 0, stream>>>(
        A7, W2t, b2, o_out, o_ns, 512, BB, 512, 1024);
}